// Round 1
// baseline (383.527 us; speedup 1.0000x reference)
//
#include <hip/hip_runtime.h>

typedef __attribute__((ext_vector_type(8))) short short8;
typedef __attribute__((ext_vector_type(4))) float f32x4;

#define MFMA16(a, b, c) __builtin_amdgcn_mfma_f32_16x16x32_bf16((a), (b), (c), 0, 0, 0)

__device__ __forceinline__ unsigned short f2b(float f) {
  union { float f; unsigned u; } v; v.f = f;
  return (unsigned short)((v.u + 0x7FFFu + ((v.u >> 16) & 1u)) >> 16);  // RNE
}

// ---------------- prep kernels ----------------
// wqkvT[wcol][k] = bf16(qkv_w[k][wcol]) with SCALE folded into Q columns (wcol<256)
__global__ void prep_wqkv(const float* __restrict__ qkv_w, unsigned short* __restrict__ wq) {
  int idx = blockIdx.x * 256 + threadIdx.x;   // 768*256
  int wcol = idx >> 8, k = idx & 255;
  float v = qkv_w[k * 768 + wcol];
  if (wcol < 256) v *= 0.125f;
  wq[idx] = f2b(v);
}

__global__ void prep_wproj(const float* __restrict__ proj_w, unsigned short* __restrict__ wp) {
  int idx = blockIdx.x * 256 + threadIdx.x;   // 256*256
  int col = idx >> 8, k = idx & 255;
  wp[idx] = f2b(proj_w[k * 256 + col]);
}

// comb[w][h][i][j] (64x4x64x64 f32): mask+bias for valid, 0 for pad rows, -1e30 for pad cols
__global__ void prep_comb(const float* __restrict__ mask, const float* __restrict__ bias_table,
                          const int* __restrict__ rel_index, float* __restrict__ comb) {
  int idx = blockIdx.x * 256 + threadIdx.x;   // 64*4*64*64 = 1048576
  int j = idx & 63, i = (idx >> 6) & 63, h = (idx >> 12) & 3, w = idx >> 14;
  float v;
  if (j >= 49) v = -1e30f;
  else if (i >= 49) v = 0.f;
  else v = mask[(w * 49 + i) * 49 + j] + bias_table[rel_index[i * 49 + j] * 4 + h];
  comb[idx] = v;
}

// ---------------- fused window-attention kernel ----------------
// LDS layout (ushort units). Row strides chosen so stride%32 dwords == 4 (2-way conflicts only).
#define XS   0        // [64][264]  x staged as bf16; later aliased by attention output O
#define XLD  264
#define QS   16896    // [64][72]   Q (rows=token, cols=dim, scaled)
#define KS   21504    // [64][72]   K
#define VT   26112    // [64][72]   V transposed: [dim][token]
#define PS   30720    // [64][72]   P (softmax probs), per-wave row slices
#define SLD  72
#define LDS_TOT 35328 // ushorts = 70656 B -> 2 blocks/CU

__global__ __launch_bounds__(256, 2) void win_attn(
    const float* __restrict__ x, const float* __restrict__ qkv_b,
    const float* __restrict__ proj_b, const unsigned short* __restrict__ wq,
    const unsigned short* __restrict__ wp, const float* __restrict__ comb,
    float* __restrict__ out)
{
  __shared__ alignas(16) unsigned short lds[LDS_TOT];
  const int b = blockIdx.x, tid = threadIdx.x;
  const int wv = tid >> 6, l = tid & 63, g = l >> 4, c = l & 15;

  // ---- Phase A: stage x[b] -> bf16 LDS, rows >= 49 zeroed ----
  {
    const float4* xb = (const float4*)(x + (size_t)b * (49 * 256));
    #pragma unroll
    for (int it = 0; it < 16; ++it) {
      int idx = tid + it * 256, row = idx >> 6, c4 = idx & 63;
      float4 v = make_float4(0.f, 0.f, 0.f, 0.f);
      if (row < 49) v = xb[row * 64 + c4];
      ushort4 pk = make_ushort4(f2b(v.x), f2b(v.y), f2b(v.z), f2b(v.w));
      *(ushort4*)&lds[XS + row * XLD + c4 * 4] = pk;
    }
  }
  __syncthreads();

  f32x4 zero4 = {0.f, 0.f, 0.f, 0.f};
  f32x4 oacc[4][4];
  #pragma unroll
  for (int h = 0; h < 4; ++h)
    #pragma unroll
    for (int nd = 0; nd < 4; ++nd) oacc[h][nd] = zero4;

  #pragma unroll
  for (int h = 0; h < 4; ++h) {
    // ---- B1: QKV GEMM for head h; this wave computes a 16-col slice of Q,K,V ----
    #pragma unroll
    for (int dst = 0; dst < 3; ++dst) {
      const int wcol0 = dst * 256 + h * 64 + wv * 16;
      f32x4 acc[4];
      #pragma unroll
      for (int mi = 0; mi < 4; ++mi) acc[mi] = zero4;
      #pragma unroll
      for (int ks = 0; ks < 8; ++ks) {
        const int k0 = ks * 32 + g * 8;
        short8 bf = *(const short8*)(wq + (size_t)(wcol0 + c) * 256 + k0);
        #pragma unroll
        for (int mi = 0; mi < 4; ++mi) {
          short8 af = *(const short8*)&lds[XS + (mi * 16 + c) * XLD + k0];
          acc[mi] = MFMA16(af, bf, acc[mi]);
        }
      }
      const float bias = qkv_b[wcol0 + c];
      const int d = wv * 16 + c;   // within-head dim of this slice
      #pragma unroll
      for (int mi = 0; mi < 4; ++mi) {
        #pragma unroll
        for (int r = 0; r < 4; ++r) {
          const int row = mi * 16 + g * 4 + r;   // token
          const unsigned short bv = f2b(acc[mi][r] + bias);
          if (dst == 0)      lds[QS + row * SLD + d] = bv;
          else if (dst == 1) lds[KS + row * SLD + d] = bv;
          else               lds[VT + d * SLD + row] = bv;   // V transposed
        }
      }
    }
    __syncthreads();

    // ---- B2: S = Q K^T for this wave's 16 query rows [16wv, 16wv+16) ----
    f32x4 sacc[4];
    #pragma unroll
    for (int ni = 0; ni < 4; ++ni) sacc[ni] = zero4;
    #pragma unroll
    for (int kk = 0; kk < 2; ++kk) {
      short8 af = *(const short8*)&lds[QS + (wv * 16 + c) * SLD + kk * 32 + g * 8];
      #pragma unroll
      for (int ni = 0; ni < 4; ++ni) {
        short8 bf = *(const short8*)&lds[KS + (ni * 16 + c) * SLD + kk * 32 + g * 8];
        sacc[ni] = MFMA16(af, bf, sacc[ni]);
      }
    }

    // ---- B3: +bias+mask (comb), row softmax ----
    const float* cb = comb + (((size_t)(b & 63) * 4 + h) << 12);
    float sv[4][4];
    #pragma unroll
    for (int ni = 0; ni < 4; ++ni)
      #pragma unroll
      for (int r = 0; r < 4; ++r)
        sv[ni][r] = sacc[ni][r] + cb[(wv * 16 + g * 4 + r) * 64 + ni * 16 + c];

    #pragma unroll
    for (int r = 0; r < 4; ++r) {
      float m = fmaxf(fmaxf(sv[0][r], sv[1][r]), fmaxf(sv[2][r], sv[3][r]));
      #pragma unroll
      for (int off = 8; off; off >>= 1) m = fmaxf(m, __shfl_xor(m, off, 16));
      float p[4], s = 0.f;
      #pragma unroll
      for (int ni = 0; ni < 4; ++ni) { p[ni] = __expf(sv[ni][r] - m); s += p[ni]; }
      #pragma unroll
      for (int off = 8; off; off >>= 1) s += __shfl_xor(s, off, 16);
      const float inv = 1.0f / s;
      const int row = wv * 16 + g * 4 + r;
      #pragma unroll
      for (int ni = 0; ni < 4; ++ni)
        lds[PS + row * SLD + ni * 16 + c] = f2b(p[ni] * inv);
    }

    // ---- B4: O_h = P V (this wave's 16 rows; accumulate per-head in regs) ----
    #pragma unroll
    for (int kk = 0; kk < 2; ++kk) {
      short8 af = *(const short8*)&lds[PS + (wv * 16 + c) * SLD + kk * 32 + g * 8];
      #pragma unroll
      for (int nd = 0; nd < 4; ++nd) {
        short8 bf = *(const short8*)&lds[VT + (nd * 16 + c) * SLD + kk * 32 + g * 8];
        oacc[h][nd] = MFMA16(af, bf, oacc[h][nd]);
      }
    }
    __syncthreads();   // protect QS/KS/VT before next head overwrites
  }

  // ---- Phase C: write O bf16 into XS region (x is dead now) ----
  #pragma unroll
  for (int h = 0; h < 4; ++h)
    #pragma unroll
    for (int nd = 0; nd < 4; ++nd)
      #pragma unroll
      for (int r = 0; r < 4; ++r)
        lds[XS + (wv * 16 + g * 4 + r) * XLD + h * 64 + nd * 16 + c] = f2b(oacc[h][nd][r]);
  __syncthreads();

  // ---- Phase D: out = O @ proj_w + proj_b (this wave: 64 output cols) ----
  #pragma unroll
  for (int nj = 0; nj < 4; ++nj) {
    const int col0 = wv * 64 + nj * 16;
    f32x4 pacc[4];
    #pragma unroll
    for (int mi = 0; mi < 4; ++mi) pacc[mi] = zero4;
    #pragma unroll
    for (int ks = 0; ks < 8; ++ks) {
      const int k0 = ks * 32 + g * 8;
      short8 bf = *(const short8*)(wp + (size_t)(col0 + c) * 256 + k0);
      #pragma unroll
      for (int mi = 0; mi < 4; ++mi) {
        short8 af = *(const short8*)&lds[XS + (mi * 16 + c) * XLD + k0];
        pacc[mi] = MFMA16(af, bf, pacc[mi]);
      }
    }
    const float pb = proj_b[col0 + c];
    #pragma unroll
    for (int mi = 0; mi < 4; ++mi) {
      #pragma unroll
      for (int r = 0; r < 4; ++r) {
        const int row = mi * 16 + g * 4 + r;
        if (row < 49)
          out[((size_t)b * 49 + row) * 256 + col0 + c] = pacc[mi][r] + pb;
      }
    }
  }
}

extern "C" void kernel_launch(void* const* d_in, const int* in_sizes, int n_in,
                              void* d_out, int out_size, void* d_ws, size_t ws_size,
                              hipStream_t stream) {
  const float* x          = (const float*)d_in[0];
  const float* mask       = (const float*)d_in[1];
  const float* qkv_w      = (const float*)d_in[2];
  const float* qkv_b      = (const float*)d_in[3];
  const float* proj_w     = (const float*)d_in[4];
  const float* proj_b     = (const float*)d_in[5];
  const float* bias_table = (const float*)d_in[6];
  const int*   rel_index  = (const int*)d_in[7];
  float* out = (float*)d_out;

  unsigned short* wq = (unsigned short*)d_ws;            // 768*256 bf16
  unsigned short* wp = wq + 768 * 256;                   // 256*256 bf16
  float* comb = (float*)(wp + 256 * 256);                // 64*4*64*64 f32 (~4 MB)

  prep_wqkv<<<768, 256, 0, stream>>>(qkv_w, wq);
  prep_wproj<<<256, 256, 0, stream>>>(proj_w, wp);
  prep_comb<<<4096, 256, 0, stream>>>(mask, bias_table, rel_index, comb);
  win_attn<<<4096, 256, 0, stream>>>(x, qkv_b, proj_b, wq, wp, comb, out);
}